// Round 1
// baseline (147.134 us; speedup 1.0000x reference)
//
#include <hip/hip_runtime.h>
#include <math.h>

// ---------------- problem constants ----------------
#define NROWS  23328           // 8 * 54 * 54
#define SPAT   2916            // 54*54 rows per batch
#define HIN    56
#define IMG    3136            // 56*56
#define CIMG   200704          // 64*3136
#define NOUT   2985984         // 23328*128
#define RBPB   46              // 64-row blocks per batch (last has 36 valid)
#define NCH    27              // chunks per K-half (81 K32-steps / 3)

// ---------------- ws layout (bytes) ----------------
#define W2_OFF    0u                         // [648][128][8] bf16 = 1327104
#define ACT8_OFF  1335296u                   // [NPIX][8] bf16 = 25690112
#define SILU_OFF  27025408u                  // [NHW][64] bf16 = 3211264
#define PART_OFF  30236672u                  // [2][NOUT] f32 = 23887872
#define WS_NEED   (PART_OFF + 2u * NOUT * 4u)   // 54.1 MB (proven available)

// prep idx ranges
#define R_SIL_END  200704
#define R_W2_END   864256                    // +663552
#define R_ACT_END  1265664                   // +401408

typedef __bf16 bf16x8 __attribute__((ext_vector_type(8)));
typedef float  floatx4 __attribute__((ext_vector_type(4)));

#define GL2LDS(SRC, DST) __builtin_amdgcn_global_load_lds( \
    (const __attribute__((address_space(1))) unsigned int*)(SRC), \
    (__attribute__((address_space(3))) unsigned int*)(DST), 16, 0, 0)

__device__ __forceinline__ float silu_f(float p) {
    return p / (1.f + __expf(-p));
}

__device__ __forceinline__ bf16x8 bases8(float p) {
    float u  = p * 2.5f + 5.5f;              // uniform grid [-2.2,2.2], h=0.4
    float fk = floorf(u);
    int   kk = (int)fk;
    float t  = u - fk;
    float t2 = t * t, t3 = t2 * t;
    float omt = 1.f - t;
    float w0 = omt * omt * omt * (1.f / 6.f);
    float w1 = (3.f * t3 - 6.f * t2 + 4.f) * (1.f / 6.f);
    float w2 = (-3.f * t3 + 3.f * t2 + 3.f * t + 1.f) * (1.f / 6.f);
    float w3 = t3 * (1.f / 6.f);
    bool inr = (u >= 0.f) && (u < 11.f);
    bf16x8 v;
#pragma unroll
    for (int g = 0; g < 8; ++g) {
        int d = kk - g;
        float val = (d == 3) ? w0 : (d == 2) ? w1
                  : (d == 1) ? w2 : (d == 0) ? w3 : 0.f;
        v[g] = (__bf16)(inr ? val : 0.f);
    }
    return v;
}

// ---------------------------------------------------------------------------
// Prep: silu transpose, W2 planes ([g][cout][8], g = k/8), act8 planes.
// ---------------------------------------------------------------------------
__global__ __launch_bounds__(256) void prep_kernel(
    const float* __restrict__ x, const float* __restrict__ bw,
    const float* __restrict__ sw, const float* __restrict__ sc,
    char* __restrict__ ws)
{
    __bf16* W2    = (__bf16*)(ws + W2_OFF);
    __bf16* act8  = (__bf16*)(ws + ACT8_OFF);
    __bf16* silu_t= (__bf16*)(ws + SILU_OFF);

    int idx = blockIdx.x * 256 + threadIdx.x;
    if (idx < R_SIL_END) {
        int c8 = idx & 7;
        int r  = idx >> 3;                   // b*IMG + hw
        int b  = r / IMG;
        int hw = r - b * IMG;
        const float* xb = x + b * CIMG + (c8 * 8) * IMG + hw;
        bf16x8 v;
#pragma unroll
        for (int j = 0; j < 8; ++j) v[j] = (__bf16)silu_f(xb[j * IMG]);
        *(bf16x8*)(silu_t + (size_t)r * 64 + c8 * 8) = v;
    } else if (idx < R_W2_END) {
        int iw = idx - R_SIL_END;
        int j  = iw & 7;
        int o  = (iw >> 3) & 127;
        int g  = iw >> 10;                   // 0..647
        float val;
        if (g < 576) {
            val = sw[(o * 576 + g) * 8 + j] * sc[o * 576 + g];
        } else {
            int eb = g - 576;
            int rs = eb >> 3;
            int c  = (eb & 7) * 8 + j;
            val = bw[o * 576 + c * 9 + rs];
        }
        W2[iw] = (__bf16)val;
    } else if (idx < R_ACT_END) {
        int i4 = idx - R_W2_END;
        float4 p = ((const float4*)x)[i4];
        __bf16* dst = act8 + (size_t)i4 * 32;
        *(bf16x8*)(dst)      = bases8(p.x);
        *(bf16x8*)(dst + 8)  = bases8(p.y);
        *(bf16x8*)(dst + 16) = bases8(p.z);
        *(bf16x8*)(dst + 24) = bases8(p.w);
    }
}

// ---------------------------------------------------------------------------
// GEMM: 736 blocks = 8 batches x 46 row-blocks x 2 K-halves, 512 threads
// (8 waves). batch = blockIdx & 7 -> batch-per-XCD L2 residency.
// Block = 64 rows x 128 couts x half-K; wave = 32 rows x 32 couts (2x2 acc).
//
// Pipeline (T3+T4+T5): 3 LDS buffers, depth-2 global_load_lds prefetch,
// raw s_barrier + per-wave COUNTED s_waitcnt vmcnt(2|1) (never 0 mid-loop),
// W2 fragments double-buffered in registers one chunk ahead, setprio around
// the MFMA cluster. One barrier per 96-K chunk, no full vm drain.
//
// vmcnt ledger (per wave, in issue order at top of body i):
//   [gl2lds chunk i (2|1), W-regs chunk i (6), gl2lds chunk i+1 (2|1)]
// vmcnt completes oldest-first, so waiting vmcnt(2|1) guarantees chunk i's
// LDS data (and chunk i's W regs) landed while chunk i+1's prefetch stays
// in flight across the barrier. Wait-BEFORE-barrier gives every wave the
// cross-wave staging guarantee. stage(i+2) overwrites buf[(i-1)%3], whose
// last readers finished their ds_reads before entering this barrier -> safe.
// ---------------------------------------------------------------------------
template <int MODE>
__global__ __launch_bounds__(512, 4) void kan_gemm(
    char* __restrict__ ws, float* __restrict__ outp)
{
    const __bf16* W2     = (const __bf16*)(ws + W2_OFF);
    const __bf16* act8   = (const __bf16*)(ws + ACT8_OFF);
    const __bf16* silu_t = (const __bf16*)(ws + SILU_OFF);
    float*        part   = (float*)(ws + PART_OFF);

    __shared__ __align__(16) char As[3][12 * 64 * 16];   // 36,864 B

    const int tid   = threadIdx.x;
    const int lane  = tid & 63;
    const int wave  = tid >> 6;          // 0..7
    const int quad  = lane >> 4;
    const int l16   = lane & 15;
    const int coutg = wave & 3;          // cout group of 32
    const int rowg  = wave >> 2;         // 0..1 row group of 32

    const int batch = blockIdx.x & 7;    // XCD affinity (round-robin %8)
    const int t2    = blockIdx.x >> 3;   // 0..91
    const int half  = t2 & 1;
    const int rb    = t2 >> 1;           // 0..45
    const int row0  = rb * 64;           // within batch

    // staging identity: lane = local row, clamped to batch range
    const int rl0 = row0 + lane;
    const int rcl = rl0 < SPAT ? rl0 : SPAT - 1;
    const int ohh = rcl / 54, oww = rcl - (rcl / 54) * 54;
    const size_t pb = (size_t)batch * CIMG + ohh * HIN + oww;  // pixel index
    const size_t sb = ((size_t)batch * IMG + ohh * HIN + oww) * 64;

    floatx4 acc[2][2] = {};
    bf16x8 wbufA[6], wbufB[6];           // W fragments, double-buffered

    auto stage = [&](int chunkAbs, int buf) {
        int gbase = chunkAbs * 12;
#pragma unroll
        for (int j = 0; j < 2; ++j) {
            int gl = j ? 8 + wave : wave;    // LDS slot 0..11 (wave-uniform)
            if (j && wave >= 4) break;
            int g  = gbase + gl;             // global k/8 index 0..647
            const char* src;
            if (g < 576) {                   // spline planes
                int c  = g / 9;
                int rs = g - 9 * c;
                int rw = rs / 3;
                int off = c * IMG + rw * HIN + (rs - rw * 3);
                src = (const char*)(act8 + (pb + off) * 8);
            } else {                         // base/silu planes
                int eb = g - 576;
                int rs = eb >> 3;
                int rw = rs / 3;
                int off = (rw * HIN + (rs - rw * 3)) * 64 + (eb & 7) * 8;
                src = (const char*)(silu_t + sb + off);
            }
            GL2LDS(src, &As[buf][gl * 1024]);
        }
    };

    auto loadW = [&](int chunkAbs, bf16x8* w) {
#pragma unroll
        for (int ks = 0; ks < 3; ++ks) {
            int gq = (chunkAbs * 3 + ks) * 4 + quad;
#pragma unroll
            for (int nt = 0; nt < 2; ++nt)
                w[ks * 2 + nt] = *(const bf16x8*)(W2 +
                    ((size_t)gq * 128 + coutg * 32 + nt * 16 + l16) * 8);
        }
    };

    const int cstart = half * NCH;

    // prologue: stage chunks 0,1 and pre-load W regs for chunk 0
    stage(cstart,     0);
    stage(cstart + 1, 1);
    loadW(cstart, wbufA);

    auto body = [&](int i, bf16x8* wcur, bf16x8* wnxt) {
        // counted wait: chunk i's own gl2lds done, chunk i+1's stay in flight
        if (i < NCH - 1) {
            if (wave < 4) asm volatile("s_waitcnt vmcnt(2)" ::: "memory");
            else          asm volatile("s_waitcnt vmcnt(1)" ::: "memory");
        } else {
            asm volatile("s_waitcnt vmcnt(0)" ::: "memory");
        }
        __builtin_amdgcn_sched_barrier(0);
        __builtin_amdgcn_s_barrier();
        __builtin_amdgcn_sched_barrier(0);

        if (i + 1 < NCH) loadW(cstart + i + 1, wnxt);     // W regs, 1 ahead
        if (i + 2 < NCH) stage(cstart + i + 2, (i + 2) % 3); // LDS, 2 ahead

        const char* Ab = (const char*)As[i % 3];
        __builtin_amdgcn_s_setprio(1);
#pragma unroll
        for (int ks = 0; ks < 3; ++ks) {
            bf16x8 afr[2];
#pragma unroll
            for (int mt = 0; mt < 2; ++mt)
                afr[mt] = *(const bf16x8*)(Ab +
                    ((ks * 4 + quad) * 64 + rowg * 32 + mt * 16 + l16) * 16);
#pragma unroll
            for (int mt = 0; mt < 2; ++mt)
#pragma unroll
                for (int nt = 0; nt < 2; ++nt)
                    acc[mt][nt] = __builtin_amdgcn_mfma_f32_16x16x32_bf16(
                        wcur[ks * 2 + nt], afr[mt], acc[mt][nt], 0, 0, 0);
        }
        __builtin_amdgcn_s_setprio(0);
    };

    // 2-unrolled so wbufA/wbufB roles are compile-time (no dynamic indexing)
    for (int ii = 0; ii + 1 < NCH; ii += 2) {
        body(ii,     wbufA, wbufB);
        body(ii + 1, wbufB, wbufA);
    }
    body(NCH - 1, wbufA, wbufB);   // NCH-1 = 26 (even) -> uses wbufA

    // epilogue: D col(l16) = local row, D row(quad*4+r) = cout -> coalesced
#pragma unroll
    for (int mt = 0; mt < 2; ++mt) {
        int rl = row0 + rowg * 32 + mt * 16 + l16;   // row within batch
        if (rl < SPAT) {
#pragma unroll
            for (int nt = 0; nt < 2; ++nt) {
#pragma unroll
                for (int r = 0; r < 4; ++r) {
                    int o = coutg * 32 + nt * 16 + quad * 4 + r;
                    size_t idx = (size_t)(batch * 128 + o) * SPAT + rl;
                    float v = acc[mt][nt][r];
                    if (MODE == 0) part[(size_t)half * NOUT + idx] = v;
                    else           atomicAdd(&outp[idx], v);
                }
            }
        }
    }
}

__global__ __launch_bounds__(256) void reduce_kernel(
    const char* __restrict__ ws, float* __restrict__ outp)
{
    const floatx4* p0 = (const floatx4*)(ws + PART_OFF);
    const floatx4* p1 = p0 + NOUT / 4;
    int i = blockIdx.x * 256 + threadIdx.x;   // grid covers NOUT/4 exactly
    floatx4 a = p0[i], b = p1[i];
    ((floatx4*)outp)[i] = (floatx4){a[0] + b[0], a[1] + b[1],
                                    a[2] + b[2], a[3] + b[3]};
}

__global__ __launch_bounds__(256) void zero_kernel(float* __restrict__ outp)
{
    int i = blockIdx.x * 256 + threadIdx.x;
    ((floatx4*)outp)[i] = (floatx4){0.f, 0.f, 0.f, 0.f};
}

extern "C" void kernel_launch(void* const* d_in, const int* in_sizes, int n_in,
                              void* d_out, int out_size, void* d_ws, size_t ws_size,
                              hipStream_t stream) {
    const float* x  = (const float*)d_in[0];
    const float* bw = (const float*)d_in[1];
    const float* sw = (const float*)d_in[2];
    const float* sc = (const float*)d_in[3];
    float* out = (float*)d_out;
    char*  ws  = (char*)d_ws;

    prep_kernel<<<R_ACT_END / 256, 256, 0, stream>>>(x, bw, sw, sc, ws);

    if (ws_size >= WS_NEED) {
        kan_gemm<0><<<8 * RBPB * 2, 512, 0, stream>>>(ws, out);
        reduce_kernel<<<NOUT / 4 / 256, 256, 0, stream>>>(ws, out);
    } else {
        zero_kernel<<<NOUT / 4 / 256, 256, 0, stream>>>(out);
        kan_gemm<1><<<8 * RBPB * 2, 512, 0, stream>>>(ws, out);
    }
}

// Round 2
// 145.803 us; speedup vs baseline: 1.0091x; 1.0091x over previous
//
#include <hip/hip_runtime.h>
#include <math.h>

// ---------------- problem constants ----------------
#define NROWS  23328           // 8 * 54 * 54
#define SPAT   2916            // 54*54 rows per batch
#define HIN    56
#define IMG    3136            // 56*56
#define CIMG   200704          // 64*3136
#define NOUT   2985984         // 23328*128
#define RBPB   46              // 64-row blocks per batch (last has 36 valid)
#define NCH    27              // chunks per K-half (81 K32-steps / 3)

// ---------------- ws layout (bytes) ----------------
#define W2_OFF    0u                         // [648][128][8] bf16 = 1327104
#define ACT8_OFF  1335296u                   // [NPIX][8] bf16 = 25690112
#define SILU_OFF  27025408u                  // [NHW][64] bf16 = 3211264
#define PART_OFF  30236672u                  // [2][NOUT] f32 = 23887872
#define WS_NEED   (PART_OFF + 2u * NOUT * 4u)   // 54.1 MB (proven available)

// prep idx ranges
#define R_SIL_END  200704
#define R_W2_END   864256                    // +663552
#define R_ACT_END  1265664                   // +401408

typedef __bf16 bf16x8 __attribute__((ext_vector_type(8)));
typedef float  floatx4 __attribute__((ext_vector_type(4)));

#define GL2LDS(SRC, DST) __builtin_amdgcn_global_load_lds( \
    (const __attribute__((address_space(1))) unsigned int*)(SRC), \
    (__attribute__((address_space(3))) unsigned int*)(DST), 16, 0, 0)

__device__ __forceinline__ float silu_f(float p) {
    return p / (1.f + __expf(-p));
}

__device__ __forceinline__ bf16x8 bases8(float p) {
    float u  = p * 2.5f + 5.5f;              // uniform grid [-2.2,2.2], h=0.4
    float fk = floorf(u);
    int   kk = (int)fk;
    float t  = u - fk;
    float t2 = t * t, t3 = t2 * t;
    float omt = 1.f - t;
    float w0 = omt * omt * omt * (1.f / 6.f);
    float w1 = (3.f * t3 - 6.f * t2 + 4.f) * (1.f / 6.f);
    float w2 = (-3.f * t3 + 3.f * t2 + 3.f * t + 1.f) * (1.f / 6.f);
    float w3 = t3 * (1.f / 6.f);
    bool inr = (u >= 0.f) && (u < 11.f);
    bf16x8 v;
#pragma unroll
    for (int g = 0; g < 8; ++g) {
        int d = kk - g;
        float val = (d == 3) ? w0 : (d == 2) ? w1
                  : (d == 1) ? w2 : (d == 0) ? w3 : 0.f;
        v[g] = (__bf16)(inr ? val : 0.f);
    }
    return v;
}

// ---------------------------------------------------------------------------
// Prep: silu transpose, W2 planes ([g][cout][8], g = k/8), act8 planes.
// ---------------------------------------------------------------------------
__global__ __launch_bounds__(256) void prep_kernel(
    const float* __restrict__ x, const float* __restrict__ bw,
    const float* __restrict__ sw, const float* __restrict__ sc,
    char* __restrict__ ws)
{
    __bf16* W2    = (__bf16*)(ws + W2_OFF);
    __bf16* act8  = (__bf16*)(ws + ACT8_OFF);
    __bf16* silu_t= (__bf16*)(ws + SILU_OFF);

    int idx = blockIdx.x * 256 + threadIdx.x;
    if (idx < R_SIL_END) {
        int c8 = idx & 7;
        int r  = idx >> 3;                   // b*IMG + hw
        int b  = r / IMG;
        int hw = r - b * IMG;
        const float* xb = x + b * CIMG + (c8 * 8) * IMG + hw;
        bf16x8 v;
#pragma unroll
        for (int j = 0; j < 8; ++j) v[j] = (__bf16)silu_f(xb[j * IMG]);
        *(bf16x8*)(silu_t + (size_t)r * 64 + c8 * 8) = v;
    } else if (idx < R_W2_END) {
        int iw = idx - R_SIL_END;
        int j  = iw & 7;
        int o  = (iw >> 3) & 127;
        int g  = iw >> 10;                   // 0..647
        float val;
        if (g < 576) {
            val = sw[(o * 576 + g) * 8 + j] * sc[o * 576 + g];
        } else {
            int eb = g - 576;
            int rs = eb >> 3;
            int c  = (eb & 7) * 8 + j;
            val = bw[o * 576 + c * 9 + rs];
        }
        W2[iw] = (__bf16)val;
    } else if (idx < R_ACT_END) {
        int i4 = idx - R_W2_END;
        float4 p = ((const float4*)x)[i4];
        __bf16* dst = act8 + (size_t)i4 * 32;
        *(bf16x8*)(dst)      = bases8(p.x);
        *(bf16x8*)(dst + 8)  = bases8(p.y);
        *(bf16x8*)(dst + 16) = bases8(p.z);
        *(bf16x8*)(dst + 24) = bases8(p.w);
    }
}

// ---------------------------------------------------------------------------
// GEMM: 736 blocks = 8 batches x 46 row-blocks x 2 K-halves, 512 threads
// (8 waves). batch = blockIdx & 7 -> batch-per-XCD L2 residency.
// Block = 64 rows x 128 couts x half-K; wave = 32 rows x 32 couts (2x2 acc).
// A staged by async global_load_lds, double-buffered, 3 K32-steps per chunk,
// one __syncthreads per chunk (round-0 structure — compiler scheduling kept).
//
// Round-2 change vs round-0: W2 fragments are REGISTER double-buffered one
// chunk ahead (wbufA/wbufB, static roles via 2-unrolled loop). In round-0
// the 6 W global loads sat after the barrier inside each chunk — the
// compiler cannot hoist them across __syncthreads, so every chunk exposed
// the full L2/L3 latency (~300-600 cyc) before the first MFMA. Prefetching
// them one chunk ahead hides that latency under the current MFMA phase.
// ---------------------------------------------------------------------------
template <int MODE>
__global__ __launch_bounds__(512, 4) void kan_gemm(
    char* __restrict__ ws, float* __restrict__ outp)
{
    const __bf16* W2     = (const __bf16*)(ws + W2_OFF);
    const __bf16* act8   = (const __bf16*)(ws + ACT8_OFF);
    const __bf16* silu_t = (const __bf16*)(ws + SILU_OFF);
    float*        part   = (float*)(ws + PART_OFF);

    __shared__ __align__(16) char As[2][12 * 64 * 16];   // 24,576 B

    const int tid   = threadIdx.x;
    const int lane  = tid & 63;
    const int wave  = tid >> 6;          // 0..7
    const int quad  = lane >> 4;
    const int l16   = lane & 15;
    const int coutg = wave & 3;          // cout group of 32
    const int rowg  = wave >> 2;         // 0..1 row group of 32

    const int batch = blockIdx.x & 7;    // XCD affinity (round-robin %8)
    const int t2    = blockIdx.x >> 3;   // 0..91
    const int half  = t2 & 1;
    const int rb    = t2 >> 1;           // 0..45
    const int row0  = rb * 64;           // within batch

    // staging identity: lane = local row, clamped to batch range
    const int rl0 = row0 + lane;
    const int rcl = rl0 < SPAT ? rl0 : SPAT - 1;
    const int ohh = rcl / 54, oww = rcl - (rcl / 54) * 54;
    const size_t pb = (size_t)batch * CIMG + ohh * HIN + oww;  // pixel index
    const size_t sb = ((size_t)batch * IMG + ohh * HIN + oww) * 64;

    floatx4 acc[2][2] = {};
    bf16x8 wbufA[6], wbufB[6];           // W fragments, double-buffered

    auto stage = [&](int chunkAbs, int buf) {
        int gbase = chunkAbs * 12;
#pragma unroll
        for (int j = 0; j < 2; ++j) {
            int gl = j ? 8 + wave : wave;    // LDS slot 0..11 (wave-uniform)
            if (j && wave >= 4) break;
            int g  = gbase + gl;             // global k/8 index 0..647
            const char* src;
            if (g < 576) {                   // spline planes
                int c  = g / 9;
                int rs = g - 9 * c;
                int rw = rs / 3;
                int off = c * IMG + rw * HIN + (rs - rw * 3);
                src = (const char*)(act8 + (pb + off) * 8);
            } else {                         // base/silu planes
                int eb = g - 576;
                int rs = eb >> 3;
                int rw = rs / 3;
                int off = (rw * HIN + (rs - rw * 3)) * 64 + (eb & 7) * 8;
                src = (const char*)(silu_t + sb + off);
            }
            GL2LDS(src, &As[buf][gl * 1024]);
        }
    };

    auto loadW = [&](int chunkAbs, bf16x8* w) {
#pragma unroll
        for (int ks = 0; ks < 3; ++ks) {
            int gq = (chunkAbs * 3 + ks) * 4 + quad;
#pragma unroll
            for (int nt = 0; nt < 2; ++nt)
                w[ks * 2 + nt] = *(const bf16x8*)(W2 +
                    ((size_t)gq * 128 + coutg * 32 + nt * 16 + l16) * 8);
        }
    };

    auto mfma_chunk = [&](int buf, const bf16x8* w) {
        const char* Ab = (const char*)As[buf];
#pragma unroll
        for (int ks = 0; ks < 3; ++ks) {
            bf16x8 afr[2];
#pragma unroll
            for (int mt = 0; mt < 2; ++mt)
                afr[mt] = *(const bf16x8*)(Ab +
                    ((ks * 4 + quad) * 64 + rowg * 32 + mt * 16 + l16) * 16);
#pragma unroll
            for (int mt = 0; mt < 2; ++mt)
#pragma unroll
                for (int nt = 0; nt < 2; ++nt)
                    acc[mt][nt] = __builtin_amdgcn_mfma_f32_16x16x32_bf16(
                        w[ks * 2 + nt], afr[mt], acc[mt][nt], 0, 0, 0);
        }
    };

    const int cstart = half * NCH;

    // prologue: stage chunk 0, pre-load W regs for chunk 0
    stage(cstart, 0);
    loadW(cstart, wbufA);
    __syncthreads();

    // 2-unrolled so wbufA/wbufB roles are compile-time (no dynamic indexing)
    for (int ii = 0; ii < NCH; ii += 2) {
        // even chunk ii: compute from buf 0 / wbufA, prefetch ii+1 into buf1/wbufB
        if (ii + 1 < NCH) { stage(cstart + ii + 1, 1); loadW(cstart + ii + 1, wbufB); }
        mfma_chunk(0, wbufA);
        __syncthreads();
        if (ii + 1 < NCH) {
            // odd chunk ii+1: compute from buf 1 / wbufB, prefetch ii+2
            if (ii + 2 < NCH) { stage(cstart + ii + 2, 0); loadW(cstart + ii + 2, wbufA); }
            mfma_chunk(1, wbufB);
            __syncthreads();
        }
    }

    // epilogue: D col(l16) = local row, D row(quad*4+r) = cout -> coalesced
#pragma unroll
    for (int mt = 0; mt < 2; ++mt) {
        int rl = row0 + rowg * 32 + mt * 16 + l16;   // row within batch
        if (rl < SPAT) {
#pragma unroll
            for (int nt = 0; nt < 2; ++nt) {
#pragma unroll
                for (int r = 0; r < 4; ++r) {
                    int o = coutg * 32 + nt * 16 + quad * 4 + r;
                    size_t idx = (size_t)(batch * 128 + o) * SPAT + rl;
                    float v = acc[mt][nt][r];
                    if (MODE == 0) part[(size_t)half * NOUT + idx] = v;
                    else           atomicAdd(&outp[idx], v);
                }
            }
        }
    }
}

__global__ __launch_bounds__(256) void reduce_kernel(
    const char* __restrict__ ws, float* __restrict__ outp)
{
    const floatx4* p0 = (const floatx4*)(ws + PART_OFF);
    const floatx4* p1 = p0 + NOUT / 4;
    int i = blockIdx.x * 256 + threadIdx.x;   // grid covers NOUT/4 exactly
    floatx4 a = p0[i], b = p1[i];
    ((floatx4*)outp)[i] = (floatx4){a[0] + b[0], a[1] + b[1],
                                    a[2] + b[2], a[3] + b[3]};
}

__global__ __launch_bounds__(256) void zero_kernel(float* __restrict__ outp)
{
    int i = blockIdx.x * 256 + threadIdx.x;
    ((floatx4*)outp)[i] = (floatx4){0.f, 0.f, 0.f, 0.f};
}

extern "C" void kernel_launch(void* const* d_in, const int* in_sizes, int n_in,
                              void* d_out, int out_size, void* d_ws, size_t ws_size,
                              hipStream_t stream) {
    const float* x  = (const float*)d_in[0];
    const float* bw = (const float*)d_in[1];
    const float* sw = (const float*)d_in[2];
    const float* sc = (const float*)d_in[3];
    float* out = (float*)d_out;
    char*  ws  = (char*)d_ws;

    prep_kernel<<<R_ACT_END / 256, 256, 0, stream>>>(x, bw, sw, sc, ws);

    if (ws_size >= WS_NEED) {
        kan_gemm<0><<<8 * RBPB * 2, 512, 0, stream>>>(ws, out);
        reduce_kernel<<<NOUT / 4 / 256, 256, 0, stream>>>(ws, out);
    } else {
        zero_kernel<<<NOUT / 4 / 256, 256, 0, stream>>>(out);
        kan_gemm<1><<<8 * RBPB * 2, 512, 0, stream>>>(ws, out);
    }
}

// Round 3
// 144.476 us; speedup vs baseline: 1.0184x; 1.0092x over previous
//
#include <hip/hip_runtime.h>
#include <math.h>

// ---------------- problem constants ----------------
#define NROWS  23328           // 8 * 54 * 54
#define SPAT   2916            // 54*54 rows per batch
#define HIN    56
#define IMG    3136            // 56*56
#define CIMG   200704          // 64*3136
#define NOUT   2985984         // 23328*128
#define RBPB   46              // 64-row blocks per batch (last has 36 valid)
#define NCH    27              // chunks per K-half (81 K32-steps / 3)

// ---------------- ws layout (bytes) ----------------
#define W2_OFF    0u                         // [54][chunk-staging layout] = 1327104
#define ACT8_OFF  1335296u                   // [NPIX][8] bf16 = 25690112
#define SILU_OFF  27025408u                  // [NHW][64] bf16 = 3211264
#define PART_OFF  30236672u                  // [2][NOUT] f32 = 23887872
#define WS_NEED   (PART_OFF + 2u * NOUT * 4u)   // 54.1 MB (proven available)

// prep idx ranges
#define R_SIL_END  200704
#define R_W2_END   864256                    // +663552
#define R_ACT_END  1265664                   // +401408

typedef __bf16 bf16x8 __attribute__((ext_vector_type(8)));
typedef float  floatx4 __attribute__((ext_vector_type(4)));

#define GL2LDS(SRC, DST) __builtin_amdgcn_global_load_lds( \
    (const __attribute__((address_space(1))) unsigned int*)(SRC), \
    (__attribute__((address_space(3))) unsigned int*)(DST), 16, 0, 0)

__device__ __forceinline__ float silu_f(float p) {
    return p / (1.f + __expf(-p));
}

__device__ __forceinline__ bf16x8 bases8(float p) {
    float u  = p * 2.5f + 5.5f;              // uniform grid [-2.2,2.2], h=0.4
    float fk = floorf(u);
    int   kk = (int)fk;
    float t  = u - fk;
    float t2 = t * t, t3 = t2 * t;
    float omt = 1.f - t;
    float w0 = omt * omt * omt * (1.f / 6.f);
    float w1 = (3.f * t3 - 6.f * t2 + 4.f) * (1.f / 6.f);
    float w2 = (-3.f * t3 + 3.f * t2 + 3.f * t + 1.f) * (1.f / 6.f);
    float w3 = t3 * (1.f / 6.f);
    bool inr = (u >= 0.f) && (u < 11.f);
    bf16x8 v;
#pragma unroll
    for (int g = 0; g < 8; ++g) {
        int d = kk - g;
        float val = (d == 3) ? w0 : (d == 2) ? w1
                  : (d == 1) ? w2 : (d == 0) ? w3 : 0.f;
        v[g] = (__bf16)(inr ? val : 0.f);
    }
    return v;
}

// ---------------------------------------------------------------------------
// Prep: silu transpose, W2 chunk-staging layout, act8 planes.
//
// W2 layout (round-3): chunk-major, staging-linear so the GEMM can stage a
// whole 24,576 B W-chunk with linear global_load_lds and read fragments as
// lane-contiguous ds_read_b128:
//   element index = chunk*12288 + coutg*3072 + ks*1024 + nt*512
//                 + quad*128 + l16*8 + j
// where g (k/8 plane, 0..647) = chunk*12 + ks*4 + quad,
//       cout = coutg*32 + nt*16 + l16, j = 0..7.
// ---------------------------------------------------------------------------
__global__ __launch_bounds__(256) void prep_kernel(
    const float* __restrict__ x, const float* __restrict__ bw,
    const float* __restrict__ sw, const float* __restrict__ sc,
    char* __restrict__ ws)
{
    __bf16* W2    = (__bf16*)(ws + W2_OFF);
    __bf16* act8  = (__bf16*)(ws + ACT8_OFF);
    __bf16* silu_t= (__bf16*)(ws + SILU_OFF);

    int idx = blockIdx.x * 256 + threadIdx.x;
    if (idx < R_SIL_END) {
        int c8 = idx & 7;
        int r  = idx >> 3;                   // b*IMG + hw
        int b  = r / IMG;
        int hw = r - b * IMG;
        const float* xb = x + b * CIMG + (c8 * 8) * IMG + hw;
        bf16x8 v;
#pragma unroll
        for (int j = 0; j < 8; ++j) v[j] = (__bf16)silu_f(xb[j * IMG]);
        *(bf16x8*)(silu_t + (size_t)r * 64 + c8 * 8) = v;
    } else if (idx < R_W2_END) {
        int iw = idx - R_SIL_END;
        int j  = iw & 7;
        int o  = (iw >> 3) & 127;
        int g  = iw >> 10;                   // 0..647
        float val;
        if (g < 576) {
            val = sw[(o * 576 + g) * 8 + j] * sc[o * 576 + g];
        } else {
            int eb = g - 576;
            int rs = eb >> 3;
            int c  = (eb & 7) * 8 + j;
            val = bw[o * 576 + c * 9 + rs];
        }
        int chunk = g / 12;
        int r12   = g - chunk * 12;
        int ks    = r12 >> 2;
        int quad  = r12 & 3;
        int coutg = o >> 5;
        int nt    = (o >> 4) & 1;
        int l16   = o & 15;
        W2[chunk * 12288 + coutg * 3072 + ks * 1024 + nt * 512
           + quad * 128 + l16 * 8 + j] = (__bf16)val;
    } else if (idx < R_ACT_END) {
        int i4 = idx - R_W2_END;
        float4 p = ((const float4*)x)[i4];
        __bf16* dst = act8 + (size_t)i4 * 32;
        *(bf16x8*)(dst)      = bases8(p.x);
        *(bf16x8*)(dst + 8)  = bases8(p.y);
        *(bf16x8*)(dst + 16) = bases8(p.z);
        *(bf16x8*)(dst + 24) = bases8(p.w);
    }
}

// ---------------------------------------------------------------------------
// GEMM: 736 blocks = 8 batches x 46 row-blocks x 2 K-halves, 512 threads
// (8 waves). batch = blockIdx & 7 -> batch-per-XCD L2 residency.
// Block = 64 rows x 128 couts x half-K; wave = 32 rows x 32 couts (2x2 acc).
//
// Round-3 change: W is staged through LDS like A, via fire-and-forget
// global_load_lds one chunk ahead. Rationale (rounds 1-2 post-mortem):
// __syncthreads drains vmcnt to 0 every chunk, so ONLY result-free
// global_load_lds prefetch survives as useful pipelining — its latency is
// covered by the ~466-cycle MFMA phase before the drain. Register/W-global
// prefetch cannot cross the barrier. Bonus: both row-groups read W from LDS,
// halving W L2 traffic (976 -> 489 MB, off the per-XCD L2 BW knee), and the
// main loop now has zero result-carrying global loads (VGPR back down,
// 2 blocks/CU restored).
// ---------------------------------------------------------------------------
template <int MODE>
__global__ __launch_bounds__(512, 4) void kan_gemm(
    char* __restrict__ ws, float* __restrict__ outp)
{
    const __bf16* W2     = (const __bf16*)(ws + W2_OFF);
    const __bf16* act8   = (const __bf16*)(ws + ACT8_OFF);
    const __bf16* silu_t = (const __bf16*)(ws + SILU_OFF);
    float*        part   = (float*)(ws + PART_OFF);

    __shared__ __align__(16) char As[2][12 * 64 * 16];   // 24,576 B
    __shared__ __align__(16) char Wsh[2][24576];         // 49,152 B

    const int tid   = threadIdx.x;
    const int lane  = tid & 63;
    const int wave  = tid >> 6;          // 0..7
    const int quad  = lane >> 4;
    const int l16   = lane & 15;
    const int coutg = wave & 3;          // cout group of 32
    const int rowg  = wave >> 2;         // 0..1 row group of 32

    const int batch = blockIdx.x & 7;    // XCD affinity (round-robin %8)
    const int t2    = blockIdx.x >> 3;   // 0..91
    const int half  = t2 & 1;
    const int rb    = t2 >> 1;           // 0..45
    const int row0  = rb * 64;           // within batch

    // staging identity: lane = local row, clamped to batch range
    const int rl0 = row0 + lane;
    const int rcl = rl0 < SPAT ? rl0 : SPAT - 1;
    const int ohh = rcl / 54, oww = rcl - (rcl / 54) * 54;
    const size_t pb = (size_t)batch * CIMG + ohh * HIN + oww;  // pixel index
    const size_t sb = ((size_t)batch * IMG + ohh * HIN + oww) * 64;

    floatx4 acc[2][2] = {};

    auto stage = [&](int chunkAbs, int buf) {
        int gbase = chunkAbs * 12;
#pragma unroll
        for (int j = 0; j < 2; ++j) {
            int gl = j ? 8 + wave : wave;    // LDS slot 0..11 (wave-uniform)
            if (j && wave >= 4) break;
            int g  = gbase + gl;             // global k/8 index 0..647
            const char* src;
            if (g < 576) {                   // spline planes
                int c  = g / 9;
                int rs = g - 9 * c;
                int rw = rs / 3;
                int off = c * IMG + rw * HIN + (rs - rw * 3);
                src = (const char*)(act8 + (pb + off) * 8);
            } else {                         // base/silu planes
                int eb = g - 576;
                int rs = eb >> 3;
                int rw = rs / 3;
                int off = (rw * HIN + (rs - rw * 3)) * 64 + (eb & 7) * 8;
                src = (const char*)(silu_t + sb + off);
            }
            GL2LDS(src, &As[buf][gl * 1024]);
        }
    };

    auto stageW = [&](int chunkAbs, int buf) {
        const char* base = (const char*)W2 + (size_t)chunkAbs * 24576 + lane * 16;
#pragma unroll
        for (int t = 0; t < 3; ++t) {
            int slot = wave * 3 + t;         // 0..23, wave-uniform dest
            GL2LDS(base + slot * 1024, &Wsh[buf][slot * 1024]);
        }
    };

    auto mfma_chunk = [&](int buf) {
        const char* Ab = (const char*)As[buf];
        const char* Wb = (const char*)Wsh[buf] + coutg * 6144 + l16 * 16;
#pragma unroll
        for (int ks = 0; ks < 3; ++ks) {
            bf16x8 wfr[2], afr[2];
#pragma unroll
            for (int nt = 0; nt < 2; ++nt)
                wfr[nt] = *(const bf16x8*)(Wb + ks * 2048 + nt * 1024 + quad * 256);
#pragma unroll
            for (int mt = 0; mt < 2; ++mt)
                afr[mt] = *(const bf16x8*)(Ab +
                    ((ks * 4 + quad) * 64 + rowg * 32 + mt * 16 + l16) * 16);
#pragma unroll
            for (int mt = 0; mt < 2; ++mt)
#pragma unroll
                for (int nt = 0; nt < 2; ++nt)
                    acc[mt][nt] = __builtin_amdgcn_mfma_f32_16x16x32_bf16(
                        wfr[nt], afr[mt], acc[mt][nt], 0, 0, 0);
        }
    };

    const int cstart = half * NCH;

    // prologue: stage chunk 0 (A + W)
    stage(cstart, 0);
    stageW(cstart, 0);
    __syncthreads();

    for (int i = 0; i < NCH; ++i) {
        const int buf = i & 1;
        if (i + 1 < NCH) {                   // fire-and-forget prefetch
            stage(cstart + i + 1, buf ^ 1);
            stageW(cstart + i + 1, buf ^ 1);
        }
        mfma_chunk(buf);
        __syncthreads();                     // drains prefetch after MFMA phase
    }

    // epilogue: D col(l16) = local row, D row(quad*4+r) = cout -> coalesced
#pragma unroll
    for (int mt = 0; mt < 2; ++mt) {
        int rl = row0 + rowg * 32 + mt * 16 + l16;   // row within batch
        if (rl < SPAT) {
#pragma unroll
            for (int nt = 0; nt < 2; ++nt) {
#pragma unroll
                for (int r = 0; r < 4; ++r) {
                    int o = coutg * 32 + nt * 16 + quad * 4 + r;
                    size_t idx = (size_t)(batch * 128 + o) * SPAT + rl;
                    float v = acc[mt][nt][r];
                    if (MODE == 0) part[(size_t)half * NOUT + idx] = v;
                    else           atomicAdd(&outp[idx], v);
                }
            }
        }
    }
}

__global__ __launch_bounds__(256) void reduce_kernel(
    const char* __restrict__ ws, float* __restrict__ outp)
{
    const floatx4* p0 = (const floatx4*)(ws + PART_OFF);
    const floatx4* p1 = p0 + NOUT / 4;
    int i = blockIdx.x * 256 + threadIdx.x;   // grid covers NOUT/4 exactly
    floatx4 a = p0[i], b = p1[i];
    ((floatx4*)outp)[i] = (floatx4){a[0] + b[0], a[1] + b[1],
                                    a[2] + b[2], a[3] + b[3]};
}

__global__ __launch_bounds__(256) void zero_kernel(float* __restrict__ outp)
{
    int i = blockIdx.x * 256 + threadIdx.x;
    ((floatx4*)outp)[i] = (floatx4){0.f, 0.f, 0.f, 0.f};
}

extern "C" void kernel_launch(void* const* d_in, const int* in_sizes, int n_in,
                              void* d_out, int out_size, void* d_ws, size_t ws_size,
                              hipStream_t stream) {
    const float* x  = (const float*)d_in[0];
    const float* bw = (const float*)d_in[1];
    const float* sw = (const float*)d_in[2];
    const float* sc = (const float*)d_in[3];
    float* out = (float*)d_out;
    char*  ws  = (char*)d_ws;

    prep_kernel<<<R_ACT_END / 256, 256, 0, stream>>>(x, bw, sw, sc, ws);

    if (ws_size >= WS_NEED) {
        kan_gemm<0><<<8 * RBPB * 2, 512, 0, stream>>>(ws, out);
        reduce_kernel<<<NOUT / 4 / 256, 256, 0, stream>>>(ws, out);
    } else {
        zero_kernel<<<NOUT / 4 / 256, 256, 0, stream>>>(out);
        kan_gemm<1><<<8 * RBPB * 2, 512, 0, stream>>>(ws, out);
    }
}

// Round 4
// 138.240 us; speedup vs baseline: 1.0643x; 1.0451x over previous
//
#include <hip/hip_runtime.h>
#include <math.h>

// ---------------- problem constants ----------------
#define NROWS  23328           // 8 * 54 * 54
#define SPAT   2916            // 54*54 rows per batch
#define HIN    56
#define IMG    3136            // 56*56
#define CIMG   200704          // 64*3136
#define NOUT   2985984         // 23328*128
#define RBPB   23              // 128-row blocks per batch (last has 100 valid)
#define NKP    3               // K-pieces (thirds)
#define NCH    18              // chunks per K-piece (216 planes / 12)

// ---------------- ws layout (bytes) ----------------
#define W2_OFF    0u                         // [648][128][8] bf16 = 1327104
#define ACT8_OFF  1335296u                   // [NPIX][8] bf16 = 25690112
#define SILU_OFF  27025408u                  // [NHW][64] bf16 = 3211264
#define PART_OFF  30236672u                  // [3][NOUT] f32 = 35831808
#define WS_NEED   (PART_OFF + 3u * NOUT * 4u)   // 66.1 MB (MODE-1 fallback if not)

// prep idx ranges
#define R_SIL_END  200704
#define R_W2_END   864256                    // +663552
#define R_ACT_END  1265664                   // +401408

typedef __bf16 bf16x8 __attribute__((ext_vector_type(8)));
typedef float  floatx4 __attribute__((ext_vector_type(4)));

#define GL2LDS(SRC, DST) __builtin_amdgcn_global_load_lds( \
    (const __attribute__((address_space(1))) unsigned int*)(SRC), \
    (__attribute__((address_space(3))) unsigned int*)(DST), 16, 0, 0)

__device__ __forceinline__ float silu_f(float p) {
    return p / (1.f + __expf(-p));
}

__device__ __forceinline__ bf16x8 bases8(float p) {
    float u  = p * 2.5f + 5.5f;              // uniform grid [-2.2,2.2], h=0.4
    float fk = floorf(u);
    int   kk = (int)fk;
    float t  = u - fk;
    float t2 = t * t, t3 = t2 * t;
    float omt = 1.f - t;
    float w0 = omt * omt * omt * (1.f / 6.f);
    float w1 = (3.f * t3 - 6.f * t2 + 4.f) * (1.f / 6.f);
    float w2 = (-3.f * t3 + 3.f * t2 + 3.f * t + 1.f) * (1.f / 6.f);
    float w3 = t3 * (1.f / 6.f);
    bool inr = (u >= 0.f) && (u < 11.f);
    bf16x8 v;
#pragma unroll
    for (int g = 0; g < 8; ++g) {
        int d = kk - g;
        float val = (d == 3) ? w0 : (d == 2) ? w1
                  : (d == 1) ? w2 : (d == 0) ? w3 : 0.f;
        v[g] = (__bf16)(inr ? val : 0.f);
    }
    return v;
}

// ---------------------------------------------------------------------------
// Prep: silu transpose, W2 planes ([g][cout][8], g = k/8 — round-0 layout),
// act8 planes. Unchanged from round 0.
// ---------------------------------------------------------------------------
__global__ __launch_bounds__(256) void prep_kernel(
    const float* __restrict__ x, const float* __restrict__ bw,
    const float* __restrict__ sw, const float* __restrict__ sc,
    char* __restrict__ ws)
{
    __bf16* W2    = (__bf16*)(ws + W2_OFF);
    __bf16* act8  = (__bf16*)(ws + ACT8_OFF);
    __bf16* silu_t= (__bf16*)(ws + SILU_OFF);

    int idx = blockIdx.x * 256 + threadIdx.x;
    if (idx < R_SIL_END) {
        int c8 = idx & 7;
        int r  = idx >> 3;                   // b*IMG + hw
        int b  = r / IMG;
        int hw = r - b * IMG;
        const float* xb = x + b * CIMG + (c8 * 8) * IMG + hw;
        bf16x8 v;
#pragma unroll
        for (int j = 0; j < 8; ++j) v[j] = (__bf16)silu_f(xb[j * IMG]);
        *(bf16x8*)(silu_t + (size_t)r * 64 + c8 * 8) = v;
    } else if (idx < R_W2_END) {
        int iw = idx - R_SIL_END;
        int j  = iw & 7;
        int o  = (iw >> 3) & 127;
        int g  = iw >> 10;                   // 0..647
        float val;
        if (g < 576) {
            val = sw[(o * 576 + g) * 8 + j] * sc[o * 576 + g];
        } else {
            int eb = g - 576;
            int rs = eb >> 3;
            int c  = (eb & 7) * 8 + j;
            val = bw[o * 576 + c * 9 + rs];
        }
        W2[iw] = (__bf16)val;
    } else if (idx < R_ACT_END) {
        int i4 = idx - R_W2_END;
        float4 p = ((const float4*)x)[i4];
        __bf16* dst = act8 + (size_t)i4 * 32;
        *(bf16x8*)(dst)      = bases8(p.x);
        *(bf16x8*)(dst + 8)  = bases8(p.y);
        *(bf16x8*)(dst + 16) = bases8(p.z);
        *(bf16x8*)(dst + 24) = bases8(p.w);
    }
}

// ---------------------------------------------------------------------------
// GEMM: 552 blocks = 8 batches x 23 row-blocks x 3 K-pieces, 512 threads
// (8 waves). batch = blockIdx & 7 -> batch-per-XCD L2 residency.
//
// Round-4 redesign, from the per-CU pipe budget (round-3 post-mortem):
// round-0 was L2-READ-BANDWIDTH paced (1.19 GB total = 23 TB/s = 66% of the
// 34.5 TB/s L2 ceiling; MFMA 29%, LDS 36%). W L2 traffic scales as
// 1/(rows_per_wave/16), so the wave tile goes 32x32 -> 64 rows x 32 couts
// (acc 4x2): W traffic 953 -> 477 MB, A unchanged (242 MB), LDS-read/MFMA
// ratio unchanged. Block = 128 rows x 128 couts; K split in thirds to keep
// 552 blocks (2.16/CU). W stays global->VGPR (round 3 showed the LDS port
// is the next constraint — don't route W through it).
// ---------------------------------------------------------------------------
template <int MODE>
__global__ __launch_bounds__(512, 4) void kan_gemm(
    char* __restrict__ ws, float* __restrict__ outp)
{
    const __bf16* W2     = (const __bf16*)(ws + W2_OFF);
    const __bf16* act8   = (const __bf16*)(ws + ACT8_OFF);
    const __bf16* silu_t = (const __bf16*)(ws + SILU_OFF);
    float*        part   = (float*)(ws + PART_OFF);

    __shared__ __align__(16) char As[2][12 * 128 * 16];   // 2 x 24,576 B

    const int tid   = threadIdx.x;
    const int lane  = tid & 63;
    const int wave  = tid >> 6;          // 0..7
    const int quad  = lane >> 4;
    const int l16   = lane & 15;
    const int coutg = wave & 3;          // cout group of 32
    const int rowg  = wave >> 2;         // 0..1 row group of 64

    const int batch = blockIdx.x & 7;    // XCD affinity (round-robin %8)
    const int t2    = blockIdx.x >> 3;   // 0..68
    const int kp    = t2 % 3;            // K-piece
    const int rb    = t2 / 3;            // 0..22
    const int row0  = rb * 128;          // within batch

    // staging identity: this wave stages row-half rh = wave&1 of the 128-row
    // tile; lane = row within the 64-row half, clamped to batch range.
    const int rh  = wave & 1;
    const int rl0 = row0 + rh * 64 + lane;
    const int rcl = rl0 < SPAT ? rl0 : SPAT - 1;
    const int ohh = rcl / 54, oww = rcl - (rcl / 54) * 54;
    const size_t pb = (size_t)batch * CIMG + ohh * HIN + oww;  // pixel index
    const size_t sb = ((size_t)batch * IMG + ohh * HIN + oww) * 64;

    floatx4 acc[4][2] = {};

    // 24 KB A-chunk = 12 planes x 128 rows x 16 B = 24 slots of 1 KB.
    // Wave w stages slots {p*2+rh : p = t*4 + (w>>1), t=0..2} (wave-uniform
    // LDS dest, per-lane global src — gl2lds contract).
    auto stage = [&](int chunkAbs, int buf) {
        int gbase = chunkAbs * 12;
#pragma unroll
        for (int t = 0; t < 3; ++t) {
            int p = t * 4 + (wave >> 1);     // plane 0..11
            int g = gbase + p;               // global k/8 index 0..647
            const char* src;
            if (g < 576) {                   // spline planes
                int c  = g / 9;
                int rs = g - 9 * c;
                int rw = rs / 3;
                int off = c * IMG + rw * HIN + (rs - rw * 3);
                src = (const char*)(act8 + (pb + off) * 8);
            } else {                         // base/silu planes
                int eb = g - 576;
                int rs = eb >> 3;
                int rw = rs / 3;
                int off = (rw * HIN + (rs - rw * 3)) * 64 + (eb & 7) * 8;
                src = (const char*)(silu_t + sb + off);
            }
            GL2LDS(src, &As[buf][(p * 2 + rh) * 1024]);
        }
    };

    auto mfma_chunk = [&](int chunkAbs, int buf) {
        const char* Ab = (const char*)As[buf];
#pragma unroll
        for (int ks = 0; ks < 3; ++ks) {
            int gq = (chunkAbs * 3 + ks) * 4 + quad;
            bf16x8 wfr[2], afr[4];
#pragma unroll
            for (int nt = 0; nt < 2; ++nt)
                wfr[nt] = *(const bf16x8*)(W2 +
                    ((size_t)gq * 128 + coutg * 32 + nt * 16 + l16) * 8);
#pragma unroll
            for (int mt = 0; mt < 4; ++mt)
                afr[mt] = *(const bf16x8*)(Ab +
                    ((ks * 4 + quad) * 128 + rowg * 64 + mt * 16 + l16) * 16);
#pragma unroll
            for (int mt = 0; mt < 4; ++mt)
#pragma unroll
                for (int nt = 0; nt < 2; ++nt)
                    acc[mt][nt] = __builtin_amdgcn_mfma_f32_16x16x32_bf16(
                        wfr[nt], afr[mt], acc[mt][nt], 0, 0, 0);
        }
    };

    const int cstart = kp * NCH;

    stage(cstart, 0);
    __syncthreads();

    for (int i = 0; i < NCH; ++i) {
        const int buf = i & 1;
        if (i + 1 < NCH) stage(cstart + i + 1, buf ^ 1);   // async prefetch
        mfma_chunk(cstart + i, buf);
        __syncthreads();
    }

    // epilogue: D col(l16) = local row, D row(quad*4+r) = cout -> coalesced
#pragma unroll
    for (int mt = 0; mt < 4; ++mt) {
        int rl = row0 + rowg * 64 + mt * 16 + l16;   // row within batch
        if (rl < SPAT) {
#pragma unroll
            for (int nt = 0; nt < 2; ++nt) {
#pragma unroll
                for (int r = 0; r < 4; ++r) {
                    int o = coutg * 32 + nt * 16 + quad * 4 + r;
                    size_t idx = (size_t)(batch * 128 + o) * SPAT + rl;
                    float v = acc[mt][nt][r];
                    if (MODE == 0) part[(size_t)kp * NOUT + idx] = v;
                    else           atomicAdd(&outp[idx], v);
                }
            }
        }
    }
}

__global__ __launch_bounds__(256) void reduce_kernel(
    const char* __restrict__ ws, float* __restrict__ outp)
{
    const floatx4* p0 = (const floatx4*)(ws + PART_OFF);
    const floatx4* p1 = p0 + NOUT / 4;
    const floatx4* p2 = p1 + NOUT / 4;
    int i = blockIdx.x * 256 + threadIdx.x;   // grid covers NOUT/4 exactly
    floatx4 a = p0[i], b = p1[i], c = p2[i];
    ((floatx4*)outp)[i] = (floatx4){a[0] + b[0] + c[0], a[1] + b[1] + c[1],
                                    a[2] + b[2] + c[2], a[3] + b[3] + c[3]};
}

__global__ __launch_bounds__(256) void zero_kernel(float* __restrict__ outp)
{
    int i = blockIdx.x * 256 + threadIdx.x;
    ((floatx4*)outp)[i] = (floatx4){0.f, 0.f, 0.f, 0.f};
}

extern "C" void kernel_launch(void* const* d_in, const int* in_sizes, int n_in,
                              void* d_out, int out_size, void* d_ws, size_t ws_size,
                              hipStream_t stream) {
    const float* x  = (const float*)d_in[0];
    const float* bw = (const float*)d_in[1];
    const float* sw = (const float*)d_in[2];
    const float* sc = (const float*)d_in[3];
    float* out = (float*)d_out;
    char*  ws  = (char*)d_ws;

    prep_kernel<<<R_ACT_END / 256, 256, 0, stream>>>(x, bw, sw, sc, ws);

    if (ws_size >= WS_NEED) {
        kan_gemm<0><<<8 * RBPB * NKP, 512, 0, stream>>>(ws, out);
        reduce_kernel<<<NOUT / 4 / 256, 256, 0, stream>>>(ws, out);
    } else {
        zero_kernel<<<NOUT / 4 / 256, 256, 0, stream>>>(out);
        kan_gemm<1><<<8 * RBPB * NKP, 512, 0, stream>>>(ws, out);
    }
}

// Round 5
// 133.212 us; speedup vs baseline: 1.1045x; 1.0377x over previous
//
#include <hip/hip_runtime.h>
#include <math.h>

// ---------------- problem constants ----------------
#define NROWS  23328           // 8 * 54 * 54
#define SPAT   2916            // 54*54 rows per batch
#define HIN    56
#define IMG    3136            // 56*56
#define CIMG   200704          // 64*3136
#define NOUT   2985984         // 23328*128
#define RBPB   46              // 64-row blocks per batch (last has 36 valid)
#define NKP    3               // K-pieces (thirds)
#define NCH    18              // chunks per K-piece (216 planes / 12)

// ---------------- ws layout (bytes) ----------------
#define W2_OFF    0u                         // [648][128][8] bf16 = 1327104
#define ACT8_OFF  1335296u                   // [NPIX][8] bf16 = 25690112
#define SILU_OFF  27025408u                  // [NHW][64] bf16 = 3211264
#define PART_OFF  30236672u                  // [3][NOUT] f32 = 35831808
#define WS_NEED   (PART_OFF + 3u * NOUT * 4u)   // 66.1 MB (proven in round 4)

// prep idx ranges
#define R_SIL_END  200704
#define R_W2_END   864256                    // +663552
#define R_ACT_END  1265664                   // +401408

typedef __bf16 bf16x8 __attribute__((ext_vector_type(8)));
typedef float  floatx4 __attribute__((ext_vector_type(4)));

#define GL2LDS(SRC, DST) __builtin_amdgcn_global_load_lds( \
    (const __attribute__((address_space(1))) unsigned int*)(SRC), \
    (__attribute__((address_space(3))) unsigned int*)(DST), 16, 0, 0)

__device__ __forceinline__ float silu_f(float p) {
    return p / (1.f + __expf(-p));
}

__device__ __forceinline__ bf16x8 bases8(float p) {
    float u  = p * 2.5f + 5.5f;              // uniform grid [-2.2,2.2], h=0.4
    float fk = floorf(u);
    int   kk = (int)fk;
    float t  = u - fk;
    float t2 = t * t, t3 = t2 * t;
    float omt = 1.f - t;
    float w0 = omt * omt * omt * (1.f / 6.f);
    float w1 = (3.f * t3 - 6.f * t2 + 4.f) * (1.f / 6.f);
    float w2 = (-3.f * t3 + 3.f * t2 + 3.f * t + 1.f) * (1.f / 6.f);
    float w3 = t3 * (1.f / 6.f);
    bool inr = (u >= 0.f) && (u < 11.f);
    bf16x8 v;
#pragma unroll
    for (int g = 0; g < 8; ++g) {
        int d = kk - g;
        float val = (d == 3) ? w0 : (d == 2) ? w1
                  : (d == 1) ? w2 : (d == 0) ? w3 : 0.f;
        v[g] = (__bf16)(inr ? val : 0.f);
    }
    return v;
}

// ---------------------------------------------------------------------------
// Prep: silu transpose, W2 planes ([g][cout][8], g = k/8), act8 planes.
// Unchanged from round 0.
// ---------------------------------------------------------------------------
__global__ __launch_bounds__(256) void prep_kernel(
    const float* __restrict__ x, const float* __restrict__ bw,
    const float* __restrict__ sw, const float* __restrict__ sc,
    char* __restrict__ ws)
{
    __bf16* W2    = (__bf16*)(ws + W2_OFF);
    __bf16* act8  = (__bf16*)(ws + ACT8_OFF);
    __bf16* silu_t= (__bf16*)(ws + SILU_OFF);

    int idx = blockIdx.x * 256 + threadIdx.x;
    if (idx < R_SIL_END) {
        int c8 = idx & 7;
        int r  = idx >> 3;                   // b*IMG + hw
        int b  = r / IMG;
        int hw = r - b * IMG;
        const float* xb = x + b * CIMG + (c8 * 8) * IMG + hw;
        bf16x8 v;
#pragma unroll
        for (int j = 0; j < 8; ++j) v[j] = (__bf16)silu_f(xb[j * IMG]);
        *(bf16x8*)(silu_t + (size_t)r * 64 + c8 * 8) = v;
    } else if (idx < R_W2_END) {
        int iw = idx - R_SIL_END;
        int j  = iw & 7;
        int o  = (iw >> 3) & 127;
        int g  = iw >> 10;                   // 0..647
        float val;
        if (g < 576) {
            val = sw[(o * 576 + g) * 8 + j] * sc[o * 576 + g];
        } else {
            int eb = g - 576;
            int rs = eb >> 3;
            int c  = (eb & 7) * 8 + j;
            val = bw[o * 576 + c * 9 + rs];
        }
        W2[iw] = (__bf16)val;
    } else if (idx < R_ACT_END) {
        int i4 = idx - R_W2_END;
        float4 p = ((const float4*)x)[i4];
        __bf16* dst = act8 + (size_t)i4 * 32;
        *(bf16x8*)(dst)      = bases8(p.x);
        *(bf16x8*)(dst + 8)  = bases8(p.y);
        *(bf16x8*)(dst + 16) = bases8(p.z);
        *(bf16x8*)(dst + 24) = bases8(p.w);
    }
}

// ---------------------------------------------------------------------------
// GEMM: 1104 blocks = 8 batches x 46 row-blocks x 3 K-pieces, 256 threads
// (4 waves). batch = blockIdx & 7 -> batch-per-XCD L2 residency.
//
// Round-5 change (occupancy probe): rounds 0-4 showed time is invariant
// (~51 us) under traffic halving, barrier halving, and every latency fix —
// but all ran at ~2.2-2.9 blocks/CU (dispatch-capped, occupancy 29-47%),
// i.e. ~2.4 waves/SIMD: too few independent waves to overlap the MFMA
// (26%), LDS-read (36%), and VALU (25%) pipes through LDS/L3 latency.
// This round holds L2 traffic ~constant (W 488 MB via 64-row waves without
// rowg duplication, A 244 MB) and raises residency: 4-wave blocks of
// 64 rows x 128 couts x K-third, 24.6 KB LDS -> ~4.3 blocks/CU avg,
// ~17 waves/CU, finer tail, 4-wave barrier joins.
// ---------------------------------------------------------------------------
template <int MODE>
__global__ __launch_bounds__(256, 4) void kan_gemm(
    char* __restrict__ ws, float* __restrict__ outp)
{
    const __bf16* W2     = (const __bf16*)(ws + W2_OFF);
    const __bf16* act8   = (const __bf16*)(ws + ACT8_OFF);
    const __bf16* silu_t = (const __bf16*)(ws + SILU_OFF);
    float*        part   = (float*)(ws + PART_OFF);

    __shared__ __align__(16) char As[2][12 * 64 * 16];   // 2 x 12,288 B

    const int tid   = threadIdx.x;
    const int lane  = tid & 63;
    const int wave  = tid >> 6;          // 0..3 = coutg
    const int quad  = lane >> 4;
    const int l16   = lane & 15;

    const int batch = blockIdx.x & 7;    // XCD affinity (round-robin %8)
    const int t2    = blockIdx.x >> 3;   // 0..137
    const int kp    = t2 % 3;            // K-piece
    const int rb    = t2 / 3;            // 0..45
    const int row0  = rb * 64;           // within batch

    // staging identity: lane = local row, clamped to batch range
    const int rl0 = row0 + lane;
    const int rcl = rl0 < SPAT ? rl0 : SPAT - 1;
    const int ohh = rcl / 54, oww = rcl - (rcl / 54) * 54;
    const size_t pb = (size_t)batch * CIMG + ohh * HIN + oww;  // pixel index
    const size_t sb = ((size_t)batch * IMG + ohh * HIN + oww) * 64;

    floatx4 acc[4][2] = {};

    // chunk = 12 planes x 64 rows x 16 B = 12 slots of 1 KB.
    // Wave w stages planes {t*4 + w : t=0..2} (wave-uniform LDS dest).
    auto stage = [&](int chunkAbs, int buf) {
        int gbase = chunkAbs * 12;
#pragma unroll
        for (int t = 0; t < 3; ++t) {
            int p = t * 4 + wave;            // plane 0..11
            int g = gbase + p;               // global k/8 index 0..647
            const char* src;
            if (g < 576) {                   // spline planes
                int c  = g / 9;
                int rs = g - 9 * c;
                int rw = rs / 3;
                int off = c * IMG + rw * HIN + (rs - rw * 3);
                src = (const char*)(act8 + (pb + off) * 8);
            } else {                         // base/silu planes
                int eb = g - 576;
                int rs = eb >> 3;
                int rw = rs / 3;
                int off = (rw * HIN + (rs - rw * 3)) * 64 + (eb & 7) * 8;
                src = (const char*)(silu_t + sb + off);
            }
            GL2LDS(src, &As[buf][p * 1024]);
        }
    };

    auto mfma_chunk = [&](int chunkAbs, int buf) {
        const char* Ab = (const char*)As[buf];
#pragma unroll
        for (int ks = 0; ks < 3; ++ks) {
            int gq = (chunkAbs * 3 + ks) * 4 + quad;
            bf16x8 wfr[2], afr[4];
#pragma unroll
            for (int nt = 0; nt < 2; ++nt)
                wfr[nt] = *(const bf16x8*)(W2 +
                    ((size_t)gq * 128 + wave * 32 + nt * 16 + l16) * 8);
#pragma unroll
            for (int mt = 0; mt < 4; ++mt)
                afr[mt] = *(const bf16x8*)(Ab +
                    ((ks * 4 + quad) * 64 + mt * 16 + l16) * 16);
#pragma unroll
            for (int mt = 0; mt < 4; ++mt)
#pragma unroll
                for (int nt = 0; nt < 2; ++nt)
                    acc[mt][nt] = __builtin_amdgcn_mfma_f32_16x16x32_bf16(
                        wfr[nt], afr[mt], acc[mt][nt], 0, 0, 0);
        }
    };

    const int cstart = kp * NCH;

    stage(cstart, 0);
    __syncthreads();

    for (int i = 0; i < NCH; ++i) {
        const int buf = i & 1;
        if (i + 1 < NCH) stage(cstart + i + 1, buf ^ 1);   // async prefetch
        mfma_chunk(cstart + i, buf);
        __syncthreads();
    }

    // epilogue: D col(l16) = local row, D row(quad*4+r) = cout -> coalesced
#pragma unroll
    for (int mt = 0; mt < 4; ++mt) {
        int rl = row0 + mt * 16 + l16;       // row within batch
        if (rl < SPAT) {
#pragma unroll
            for (int nt = 0; nt < 2; ++nt) {
#pragma unroll
                for (int r = 0; r < 4; ++r) {
                    int o = wave * 32 + nt * 16 + quad * 4 + r;
                    size_t idx = (size_t)(batch * 128 + o) * SPAT + rl;
                    float v = acc[mt][nt][r];
                    if (MODE == 0) part[(size_t)kp * NOUT + idx] = v;
                    else           atomicAdd(&outp[idx], v);
                }
            }
        }
    }
}

__global__ __launch_bounds__(256) void reduce_kernel(
    const char* __restrict__ ws, float* __restrict__ outp)
{
    const floatx4* p0 = (const floatx4*)(ws + PART_OFF);
    const floatx4* p1 = p0 + NOUT / 4;
    const floatx4* p2 = p1 + NOUT / 4;
    int i = blockIdx.x * 256 + threadIdx.x;   // grid covers NOUT/4 exactly
    floatx4 a = p0[i], b = p1[i], c = p2[i];
    ((floatx4*)outp)[i] = (floatx4){a[0] + b[0] + c[0], a[1] + b[1] + c[1],
                                    a[2] + b[2] + c[2], a[3] + b[3] + c[3]};
}

__global__ __launch_bounds__(256) void zero_kernel(float* __restrict__ outp)
{
    int i = blockIdx.x * 256 + threadIdx.x;
    ((floatx4*)outp)[i] = (floatx4){0.f, 0.f, 0.f, 0.f};
}

extern "C" void kernel_launch(void* const* d_in, const int* in_sizes, int n_in,
                              void* d_out, int out_size, void* d_ws, size_t ws_size,
                              hipStream_t stream) {
    const float* x  = (const float*)d_in[0];
    const float* bw = (const float*)d_in[1];
    const float* sw = (const float*)d_in[2];
    const float* sc = (const float*)d_in[3];
    float* out = (float*)d_out;
    char*  ws  = (char*)d_ws;

    prep_kernel<<<R_ACT_END / 256, 256, 0, stream>>>(x, bw, sw, sc, ws);

    if (ws_size >= WS_NEED) {
        kan_gemm<0><<<8 * RBPB * NKP, 256, 0, stream>>>(ws, out);
        reduce_kernel<<<NOUT / 4 / 256, 256, 0, stream>>>(ws, out);
    } else {
        zero_kernel<<<NOUT / 4 / 256, 256, 0, stream>>>(out);
        kan_gemm<1><<<8 * RBPB * NKP, 256, 0, stream>>>(ws, out);
    }
}